// Round 2
// baseline (217.348 us; speedup 1.0000x reference)
//
#include <hip/hip_runtime.h>
#include <stdint.h>

// MultiHeadSelfAttention: x[2,2048,1024] fp32, w_qkv[1024,3072], w_proj[1024,1024], b_proj[1024]
// Pipeline: cvt/transpose -> GEMM1(qkv, bf16 MFMA) -> transpose V -> flash attention (swapped-operand,
// LDS-free, lane-local softmax) -> GEMM2(+bias)

typedef unsigned short u16;
typedef uint32_t u32;
typedef __bf16 bf16x8 __attribute__((ext_vector_type(8)));
typedef unsigned short u16x8 __attribute__((ext_vector_type(8)));
typedef float f32x4 __attribute__((ext_vector_type(4)));
typedef float f32x16 __attribute__((ext_vector_type(16)));
typedef uint32_t u32x4v __attribute__((ext_vector_type(4)));

#define DEV static __device__ __forceinline__

DEV u16 f2bf(float f) {
    uint32_t u = __float_as_uint(f);
    u += 0x7fffu + ((u >> 16) & 1u);
    return (u16)(u >> 16);
}

DEV u32 cvtpk(float lo, float hi_) {  // pack {bf16(lo), bf16(hi_)} into one dword
    u32 r;
    asm("v_cvt_pk_bf16_f32 %0, %1, %2" : "=v"(r) : "v"(lo), "v"(hi_));
    return r;
}
DEV void plswap(u32& x, u32& y) {  // x' = {x.lo, y.lo}, y' = {x.hi, y.hi} across half-waves
    asm("v_permlane32_swap_b32 %0, %1" : "+v"(x), "+v"(y));
}
DEV float exp2f_fast(float x) {
    float r;
    asm("v_exp_f32 %0, %1" : "=v"(r) : "v"(x));
    return r;
}

// LDS tiles [rows][64] bf16 (128 B rows); XOR swizzle byte ^= (row&7)<<4.
DEV void swz_store16(u16* base, int row, int col16, u16x8 v) {
    int off = (row * 128 + col16 * 16) ^ ((row & 7) << 4);
    *reinterpret_cast<u16x8*>(reinterpret_cast<char*>(base) + off) = v;
}
DEV bf16x8 swz_load16(const u16* base, int row, int kbyte) {
    int off = (row * 128 + kbyte) ^ ((row & 7) << 4);
    return *reinterpret_cast<const bf16x8*>(reinterpret_cast<const char*>(base) + off);
}

// ---------------- conversion kernels ----------------

__global__ void cvt_x_kernel(const float* __restrict__ in, u16* __restrict__ out) {
    int t = blockIdx.x * 256 + threadIdx.x;
    const float4* p = reinterpret_cast<const float4*>(in) + (size_t)t * 2;
    float4 a = p[0], b = p[1];
    u16x8 o;
    o[0] = f2bf(a.x); o[1] = f2bf(a.y); o[2] = f2bf(a.z); o[3] = f2bf(a.w);
    o[4] = f2bf(b.x); o[5] = f2bf(b.y); o[6] = f2bf(b.z); o[7] = f2bf(b.w);
    reinterpret_cast<u16x8*>(out)[t] = o;
}

// transpose fp32 [R][Cc] -> bf16 [Cc][R]
__global__ void trw_kernel(const float* __restrict__ in, u16* __restrict__ out, int R, int Cc) {
    __shared__ float T[32][33];
    int x = blockIdx.x * 32 + threadIdx.x;
    int y0 = blockIdx.y * 32;
#pragma unroll
    for (int i = 0; i < 4; i++) {
        int y = y0 + threadIdx.y + i * 8;
        T[threadIdx.y + i * 8][threadIdx.x] = in[(size_t)y * Cc + x];
    }
    __syncthreads();
    int xo = y0 + threadIdx.x;
    int yo0 = blockIdx.x * 32;
#pragma unroll
    for (int i = 0; i < 4; i++) {
        int yo = yo0 + threadIdx.y + i * 8;
        out[(size_t)yo * R + xo] = f2bf(T[threadIdx.x][threadIdx.y + i * 8]);
    }
}

// transpose bf16 v[bh][2048][64] -> vt[bh][64][2048]
__global__ void trv_kernel(const u16* __restrict__ v, u16* __restrict__ vt) {
    __shared__ u16 T[64][72];
    int bh = blockIdx.y, t = blockIdx.x, tid = threadIdx.x;
    const u16* vb = v + (size_t)bh * 2048 * 64;
    u16* vo = vt + (size_t)bh * 64 * 2048;
#pragma unroll
    for (int i = 0; i < 2; i++) {
        int c = tid + i * 256, row = c >> 3, c8 = c & 7;
        u16x8 a = *reinterpret_cast<const u16x8*>(vb + (size_t)(t * 64 + row) * 64 + c8 * 8);
#pragma unroll
        for (int j = 0; j < 8; j++) T[row][c8 * 8 + j] = a[j];
    }
    __syncthreads();
#pragma unroll
    for (int i = 0; i < 2; i++) {
        int c = tid + i * 256, drow = c >> 3, c8 = c & 7;
        u16x8 o;
#pragma unroll
        for (int j = 0; j < 8; j++) o[j] = T[c8 * 8 + j][drow];
        *reinterpret_cast<u16x8*>(vo + (size_t)drow * 2048 + t * 64 + c8 * 8) = o;
    }
}

// ---------------- GEMM: A[M,1024] bf16 row-major x Bt[N,1024] bf16 row-major ----------------

template <int EPI>
__global__ __launch_bounds__(256, 2) void gemm_kernel(
    const u16* __restrict__ A, const u16* __restrict__ Bt, int ntiles,
    u16* __restrict__ o_q, u16* __restrict__ o_k, u16* __restrict__ o_v,
    float* __restrict__ o_f, const float* __restrict__ bias) {
    __shared__ __align__(16) u16 Al[128 * 64];
    __shared__ __align__(16) u16 Bl[128 * 64];
    int tid = threadIdx.x;
    int bm = blockIdx.x / ntiles, bn = blockIdx.x % ntiles;
    int lane = tid & 63, w = tid >> 6;
    int wr = w >> 1, wc = w & 1;
    int l15 = lane & 15, lhi = lane >> 4;
    const int K = 1024;

    f32x4 acc[4][4];
#pragma unroll
    for (int i = 0; i < 4; i++)
#pragma unroll
        for (int j = 0; j < 4; j++) acc[i][j] = (f32x4){0.f, 0.f, 0.f, 0.f};

    for (int kt = 0; kt < 16; ++kt) {
#pragma unroll
        for (int i = 0; i < 4; i++) {
            int c = tid + i * 256;
            int row = c >> 3, c16 = c & 7;
            u16x8 av = *reinterpret_cast<const u16x8*>(A + (size_t)(bm * 128 + row) * K + kt * 64 + c16 * 8);
            u16x8 bv = *reinterpret_cast<const u16x8*>(Bt + (size_t)(bn * 128 + row) * K + kt * 64 + c16 * 8);
            swz_store16(Al, row, c16, av);
            swz_store16(Bl, row, c16, bv);
        }
        __syncthreads();
#pragma unroll
        for (int ks = 0; ks < 2; ++ks) {
            bf16x8 af[4], bfr[4];
#pragma unroll
            for (int mi = 0; mi < 4; ++mi) af[mi] = swz_load16(Al, wr * 64 + mi * 16 + l15, ks * 64 + lhi * 16);
#pragma unroll
            for (int ni = 0; ni < 4; ++ni) bfr[ni] = swz_load16(Bl, wc * 64 + ni * 16 + l15, ks * 64 + lhi * 16);
#pragma unroll
            for (int mi = 0; mi < 4; ++mi)
#pragma unroll
                for (int ni = 0; ni < 4; ++ni)
                    acc[mi][ni] = __builtin_amdgcn_mfma_f32_16x16x32_bf16(af[mi], bfr[ni], acc[mi][ni], 0, 0, 0);
        }
        __syncthreads();
    }

    int row0 = bm * 128 + wr * 64, col0 = bn * 128 + wc * 64;
    if (EPI == 0) {
#pragma unroll
        for (int mi = 0; mi < 4; mi++)
#pragma unroll
            for (int ni = 0; ni < 4; ni++) {
                int col = col0 + ni * 16 + l15;
                int sel = col >> 10, cc = col & 1023;
                int h = cc >> 6, d = cc & 63;
#pragma unroll
                for (int j = 0; j < 4; j++) {
                    int r = row0 + mi * 16 + lhi * 4 + j;
                    int b = r >> 11, n = r & 2047;
                    size_t idx = (((size_t)(b * 16 + h)) * 2048 + n) * 64 + d;
                    float v = acc[mi][ni][j];
                    // fold softmax scale AND log2(e) into Q (flash uses exp2)
                    if (sel == 0) o_q[idx] = f2bf(v * 0.18033688f);
                    else if (sel == 1) o_k[idx] = f2bf(v);
                    else o_v[idx] = f2bf(v);
                }
            }
    } else {
#pragma unroll
        for (int mi = 0; mi < 4; mi++)
#pragma unroll
            for (int ni = 0; ni < 4; ni++) {
                int col = col0 + ni * 16 + l15;
                float bb = bias[col];
#pragma unroll
                for (int j = 0; j < 4; j++) {
                    int r = row0 + mi * 16 + lhi * 4 + j;
                    o_f[(size_t)r * 1024 + col] = acc[mi][ni][j] + bb;
                }
            }
    }
}

// ---------------- flash attention, swapped-operand, LDS-free ----------------
// grid (16 q-blocks of 128, 32 bh), 256 threads = 4 independent waves, 32 q-rows each.
// S^T = K·Q^T via mfma(A=K, B=Q): lane owns q = lane&31, kv rows (r&3)+8(r>>2)+4hi (+32 per kvb).
// O^T = V^T·P^T via mfma(A=V^T frags, B=P^T frags built in-register via cvt_pk + permlane32_swap).
__global__ __launch_bounds__(256) void flash2_kernel(
    const u16* __restrict__ qg, const u16* __restrict__ kg, const u16* __restrict__ vtg,
    u16* __restrict__ o) {
    int tid = threadIdx.x, lane = tid & 63, w = tid >> 6;
    int l31 = lane & 31, hi = lane >> 5;
    int bh = blockIdx.y;
    int q0 = blockIdx.x * 128 + w * 32;

    // Q as B-operand: qf[ds][j] = Q[q0+l31][16ds+8hi+j]
    const u16* qp = qg + ((size_t)bh * 2048 + q0 + l31) * 64 + hi * 8;
    bf16x8 qf[4];
#pragma unroll
    for (int ds = 0; ds < 4; ds++)
        qf[ds] = *reinterpret_cast<const bf16x8*>(qp + ds * 16);

    const u16* kb = kg + (size_t)bh * 2048 * 64;
    const u16* vb = vtg + (size_t)bh * 64 * 2048;

    f32x16 accO[2];
#pragma unroll
    for (int db = 0; db < 2; db++)
#pragma unroll
        for (int r = 0; r < 16; r++) accO[db][r] = 0.f;
    float m = -1e30f, lsum = 0.f;

    for (int t = 0; t < 32; t++) {
        // K as A-operand: ka[kvb][ds][j] = K[64t+32kvb+l31][16ds+8hi+j]
        const u16* kt = kb + (size_t)t * 64 * 64 + hi * 8;
        bf16x8 ka[2][4];
#pragma unroll
        for (int kvb = 0; kvb < 2; kvb++)
#pragma unroll
            for (int ds = 0; ds < 4; ds++)
                ka[kvb][ds] = *reinterpret_cast<const bf16x8*>(kt + (kvb * 32 + l31) * 64 + ds * 16);

        f32x16 s[2];
#pragma unroll
        for (int kvb = 0; kvb < 2; kvb++) {
#pragma unroll
            for (int r = 0; r < 16; r++) s[kvb][r] = 0.f;
#pragma unroll
            for (int ds = 0; ds < 4; ds++)
                s[kvb] = __builtin_amdgcn_mfma_f32_32x32x16_bf16(ka[kvb][ds], qf[ds], s[kvb], 0, 0, 0);
        }

        // V^T as A-operand for PV (issue early; latency hides under softmax):
        // va[db][ks][j] = V^T[32db+l31][64t+16ks+8hi+j]
        bf16x8 va[2][4];
        const u16* vt_ = vb + (size_t)t * 64 + hi * 8;
#pragma unroll
        for (int db = 0; db < 2; db++)
#pragma unroll
            for (int ks = 0; ks < 4; ks++)
                va[db][ks] = *reinterpret_cast<const bf16x8*>(vt_ + (size_t)(db * 32 + l31) * 2048 + ks * 16);

        // lane-local online softmax (log2 domain; Q pre-scaled by 0.125*log2e)
        float mx = s[0][0];
#pragma unroll
        for (int kvb = 0; kvb < 2; kvb++)
#pragma unroll
            for (int r = 0; r < 16; r++) mx = fmaxf(mx, s[kvb][r]);
        mx = fmaxf(mx, __shfl_xor(mx, 32));
        float mnew = fmaxf(m, mx);
        float al = exp2f_fast(m - mnew);
        m = mnew;
        float rs = 0.f;
#pragma unroll
        for (int kvb = 0; kvb < 2; kvb++)
#pragma unroll
            for (int r = 0; r < 16; r++) {
                s[kvb][r] = exp2f_fast(s[kvb][r] - mnew);
                rs += s[kvb][r];
            }
        rs += __shfl_xor(rs, 32);
        lsum = lsum * al + rs;
#pragma unroll
        for (int db = 0; db < 2; db++)
#pragma unroll
            for (int r = 0; r < 16; r++) accO[db][r] *= al;

        // P^T B-frags in-register: pb[ks][j] = P[q][16ks+8hi+j]
        bf16x8 pb[4];
#pragma unroll
        for (int kvb = 0; kvb < 2; kvb++) {
            u32 x0 = cvtpk(s[kvb][0], s[kvb][1]),   y0 = cvtpk(s[kvb][4], s[kvb][5]);
            u32 x1 = cvtpk(s[kvb][2], s[kvb][3]),   y1 = cvtpk(s[kvb][6], s[kvb][7]);
            u32 x2 = cvtpk(s[kvb][8], s[kvb][9]),   y2 = cvtpk(s[kvb][12], s[kvb][13]);
            u32 x3 = cvtpk(s[kvb][10], s[kvb][11]), y3 = cvtpk(s[kvb][14], s[kvb][15]);
            plswap(x0, y0); plswap(x1, y1); plswap(x2, y2); plswap(x3, y3);
            u32x4v plo = {x0, x1, y0, y1};
            u32x4v phi = {x2, x3, y2, y3};
            pb[2 * kvb] = __builtin_bit_cast(bf16x8, plo);
            pb[2 * kvb + 1] = __builtin_bit_cast(bf16x8, phi);
        }

#pragma unroll
        for (int db = 0; db < 2; db++)
#pragma unroll
            for (int ks = 0; ks < 4; ks++)
                accO[db] = __builtin_amdgcn_mfma_f32_32x32x16_bf16(va[db][ks], pb[ks], accO[db], 0, 0, 0);
    }

    // O^T[d][q]: lane owns q = lane&31, d = (r&3)+8(r>>2)+4hi+32db. Store d-pairs as u32.
    float inv = 1.f / lsum;
    int b = bh >> 4, h = bh & 15;
    u16* ob = o + ((size_t)(b * 2048 + q0 + l31)) * 1024 + h * 64;
#pragma unroll
    for (int db = 0; db < 2; db++)
#pragma unroll
        for (int i = 0; i < 8; i++) {
            int r = 2 * i;
            int d = (r & 3) + 8 * (r >> 2) + 4 * hi + 32 * db;
            u32 pk = cvtpk(accO[db][r] * inv, accO[db][r + 1] * inv);
            *reinterpret_cast<u32*>(ob + d) = pk;
        }
}

// ---------------- launch ----------------

extern "C" void kernel_launch(void* const* d_in, const int* in_sizes, int n_in,
                              void* d_out, int out_size, void* d_ws, size_t ws_size,
                              hipStream_t stream) {
    (void)in_sizes; (void)n_in; (void)out_size; (void)ws_size;
    const float* x = (const float*)d_in[0];
    const float* w_qkv = (const float*)d_in[1];
    const float* w_proj = (const float*)d_in[2];
    const float* b_proj = (const float*)d_in[3];
    float* out = (float*)d_out;
    char* ws = (char*)d_ws;

    u16* xb   = (u16*)(ws + 0);            // 4096x1024 bf16
    u16* wqt  = (u16*)(ws + 8388608);      // 3072x1024 bf16
    u16* wpt  = (u16*)(ws + 14680064);     // 1024x1024 bf16
    u16* qws  = (u16*)(ws + 16777216);     // [32][2048][64] bf16 (pre-scaled by 0.125*log2e)
    u16* kws  = (u16*)(ws + 25165824);
    u16* vws  = (u16*)(ws + 33554432);
    u16* vtws = (u16*)(ws + 41943040);     // [32][64][2048] bf16
    u16* attn = (u16*)(ws + 50331648);     // [4096][1024] bf16

    cvt_x_kernel<<<2048, 256, 0, stream>>>(x, xb);
    trw_kernel<<<dim3(96, 32), dim3(32, 8), 0, stream>>>(w_qkv, wqt, 1024, 3072);
    trw_kernel<<<dim3(32, 32), dim3(32, 8), 0, stream>>>(w_proj, wpt, 1024, 1024);
    gemm_kernel<0><<<32 * 24, 256, 0, stream>>>(xb, wqt, 24, qws, kws, vws, nullptr, nullptr);
    trv_kernel<<<dim3(32, 32), 256, 0, stream>>>(vws, vtws);
    flash2_kernel<<<dim3(16, 32), 256, 0, stream>>>(qws, kws, vtws, attn);
    gemm_kernel<1><<<32 * 8, 256, 0, stream>>>(attn, wpt, 8, nullptr, nullptr, nullptr, out, b_proj);
}

// Round 3
// 143.138 us; speedup vs baseline: 1.5185x; 1.5185x over previous
//
#include <hip/hip_runtime.h>
#include <stdint.h>

// MultiHeadSelfAttention: x[2,2048,1024] fp32, w_qkv[1024,3072], w_proj[1024,1024], b_proj[1024]
// Pipeline: cvt/transpose -> GEMM1(qkv, bf16 MFMA) -> transpose V -> flash attention (swapped-operand,
// LDS-staged K/V double-buffered via global_load_lds, lane-local softmax, in-register P) -> GEMM2(+bias)

typedef unsigned short u16;
typedef uint32_t u32;
typedef __bf16 bf16x8 __attribute__((ext_vector_type(8)));
typedef unsigned short u16x8 __attribute__((ext_vector_type(8)));
typedef float f32x4 __attribute__((ext_vector_type(4)));
typedef float f32x16 __attribute__((ext_vector_type(16)));
typedef uint32_t u32x4v __attribute__((ext_vector_type(4)));

#define DEV static __device__ __forceinline__

DEV u16 f2bf(float f) {
    uint32_t u = __float_as_uint(f);
    u += 0x7fffu + ((u >> 16) & 1u);
    return (u16)(u >> 16);
}

DEV u32 cvtpk(float lo, float hi_) {  // pack {bf16(lo), bf16(hi_)} into one dword
    u32 r;
    asm("v_cvt_pk_bf16_f32 %0, %1, %2" : "=v"(r) : "v"(lo), "v"(hi_));
    return r;
}
DEV void plswap(u32& x, u32& y) {  // x' = {x.lo, y.lo}, y' = {x.hi, y.hi} across half-waves
    asm("v_permlane32_swap_b32 %0, %1" : "+v"(x), "+v"(y));
}
DEV float exp2f_fast(float x) {
    float r;
    asm("v_exp_f32 %0, %1" : "=v"(r) : "v"(x));
    return r;
}

DEV void gload_lds16(const void* g, void* l) {
    __builtin_amdgcn_global_load_lds(
        (const __attribute__((address_space(1))) uint32_t*)g,
        (__attribute__((address_space(3))) uint32_t*)l, 16, 0, 0);
}

// LDS tiles [rows][64] bf16 (128 B rows); XOR swizzle byte ^= (row&7)<<4.
DEV void swz_store16(u16* base, int row, int col16, u16x8 v) {
    int off = (row * 128 + col16 * 16) ^ ((row & 7) << 4);
    *reinterpret_cast<u16x8*>(reinterpret_cast<char*>(base) + off) = v;
}
DEV bf16x8 swz_load16(const u16* base, int row, int kbyte) {
    int off = (row * 128 + kbyte) ^ ((row & 7) << 4);
    return *reinterpret_cast<const bf16x8*>(reinterpret_cast<const char*>(base) + off);
}

// ---------------- conversion kernels ----------------

__global__ void cvt_x_kernel(const float* __restrict__ in, u16* __restrict__ out) {
    int t = blockIdx.x * 256 + threadIdx.x;
    const float4* p = reinterpret_cast<const float4*>(in) + (size_t)t * 2;
    float4 a = p[0], b = p[1];
    u16x8 o;
    o[0] = f2bf(a.x); o[1] = f2bf(a.y); o[2] = f2bf(a.z); o[3] = f2bf(a.w);
    o[4] = f2bf(b.x); o[5] = f2bf(b.y); o[6] = f2bf(b.z); o[7] = f2bf(b.w);
    reinterpret_cast<u16x8*>(out)[t] = o;
}

// transpose fp32 [R][Cc] -> bf16 [Cc][R]
__global__ void trw_kernel(const float* __restrict__ in, u16* __restrict__ out, int R, int Cc) {
    __shared__ float T[32][33];
    int x = blockIdx.x * 32 + threadIdx.x;
    int y0 = blockIdx.y * 32;
#pragma unroll
    for (int i = 0; i < 4; i++) {
        int y = y0 + threadIdx.y + i * 8;
        T[threadIdx.y + i * 8][threadIdx.x] = in[(size_t)y * Cc + x];
    }
    __syncthreads();
    int xo = y0 + threadIdx.x;
    int yo0 = blockIdx.x * 32;
#pragma unroll
    for (int i = 0; i < 4; i++) {
        int yo = yo0 + threadIdx.y + i * 8;
        out[(size_t)yo * R + xo] = f2bf(T[threadIdx.x][threadIdx.y + i * 8]);
    }
}

// transpose bf16 v[bh][2048][64] -> vt[bh][64][2048]
__global__ void trv_kernel(const u16* __restrict__ v, u16* __restrict__ vt) {
    __shared__ u16 T[64][72];
    int bh = blockIdx.y, t = blockIdx.x, tid = threadIdx.x;
    const u16* vb = v + (size_t)bh * 2048 * 64;
    u16* vo = vt + (size_t)bh * 64 * 2048;
#pragma unroll
    for (int i = 0; i < 2; i++) {
        int c = tid + i * 256, row = c >> 3, c8 = c & 7;
        u16x8 a = *reinterpret_cast<const u16x8*>(vb + (size_t)(t * 64 + row) * 64 + c8 * 8);
#pragma unroll
        for (int j = 0; j < 8; j++) T[row][c8 * 8 + j] = a[j];
    }
    __syncthreads();
#pragma unroll
    for (int i = 0; i < 2; i++) {
        int c = tid + i * 256, drow = c >> 3, c8 = c & 7;
        u16x8 o;
#pragma unroll
        for (int j = 0; j < 8; j++) o[j] = T[c8 * 8 + j][drow];
        *reinterpret_cast<u16x8*>(vo + (size_t)drow * 2048 + t * 64 + c8 * 8) = o;
    }
}

// ---------------- GEMM: A[M,1024] bf16 row-major x Bt[N,1024] bf16 row-major ----------------

template <int EPI>
__global__ __launch_bounds__(256, 2) void gemm_kernel(
    const u16* __restrict__ A, const u16* __restrict__ Bt, int ntiles,
    u16* __restrict__ o_q, u16* __restrict__ o_k, u16* __restrict__ o_v,
    float* __restrict__ o_f, const float* __restrict__ bias) {
    __shared__ __align__(16) u16 Al[128 * 64];
    __shared__ __align__(16) u16 Bl[128 * 64];
    int tid = threadIdx.x;
    int bm = blockIdx.x / ntiles, bn = blockIdx.x % ntiles;
    int lane = tid & 63, w = tid >> 6;
    int wr = w >> 1, wc = w & 1;
    int l15 = lane & 15, lhi = lane >> 4;
    const int K = 1024;

    f32x4 acc[4][4];
#pragma unroll
    for (int i = 0; i < 4; i++)
#pragma unroll
        for (int j = 0; j < 4; j++) acc[i][j] = (f32x4){0.f, 0.f, 0.f, 0.f};

    for (int kt = 0; kt < 16; ++kt) {
#pragma unroll
        for (int i = 0; i < 4; i++) {
            int c = tid + i * 256;
            int row = c >> 3, c16 = c & 7;
            u16x8 av = *reinterpret_cast<const u16x8*>(A + (size_t)(bm * 128 + row) * K + kt * 64 + c16 * 8);
            u16x8 bv = *reinterpret_cast<const u16x8*>(Bt + (size_t)(bn * 128 + row) * K + kt * 64 + c16 * 8);
            swz_store16(Al, row, c16, av);
            swz_store16(Bl, row, c16, bv);
        }
        __syncthreads();
#pragma unroll
        for (int ks = 0; ks < 2; ++ks) {
            bf16x8 af[4], bfr[4];
#pragma unroll
            for (int mi = 0; mi < 4; ++mi) af[mi] = swz_load16(Al, wr * 64 + mi * 16 + l15, ks * 64 + lhi * 16);
#pragma unroll
            for (int ni = 0; ni < 4; ++ni) bfr[ni] = swz_load16(Bl, wc * 64 + ni * 16 + l15, ks * 64 + lhi * 16);
#pragma unroll
            for (int mi = 0; mi < 4; ++mi)
#pragma unroll
                for (int ni = 0; ni < 4; ++ni)
                    acc[mi][ni] = __builtin_amdgcn_mfma_f32_16x16x32_bf16(af[mi], bfr[ni], acc[mi][ni], 0, 0, 0);
        }
        __syncthreads();
    }

    int row0 = bm * 128 + wr * 64, col0 = bn * 128 + wc * 64;
    if (EPI == 0) {
#pragma unroll
        for (int mi = 0; mi < 4; mi++)
#pragma unroll
            for (int ni = 0; ni < 4; ni++) {
                int col = col0 + ni * 16 + l15;
                int sel = col >> 10, cc = col & 1023;
                int h = cc >> 6, d = cc & 63;
#pragma unroll
                for (int j = 0; j < 4; j++) {
                    int r = row0 + mi * 16 + lhi * 4 + j;
                    int b = r >> 11, n = r & 2047;
                    size_t idx = (((size_t)(b * 16 + h)) * 2048 + n) * 64 + d;
                    float v = acc[mi][ni][j];
                    // fold softmax scale AND log2(e) into Q (flash uses exp2)
                    if (sel == 0) o_q[idx] = f2bf(v * 0.18033688f);
                    else if (sel == 1) o_k[idx] = f2bf(v);
                    else o_v[idx] = f2bf(v);
                }
            }
    } else {
#pragma unroll
        for (int mi = 0; mi < 4; mi++)
#pragma unroll
            for (int ni = 0; ni < 4; ni++) {
                int col = col0 + ni * 16 + l15;
                float bb = bias[col];
#pragma unroll
                for (int j = 0; j < 4; j++) {
                    int r = row0 + mi * 16 + lhi * 4 + j;
                    o_f[(size_t)r * 1024 + col] = acc[mi][ni][j] + bb;
                }
            }
    }
}

// ---------------- flash attention: swapped-operand + LDS-staged K/V ----------------
// 512 blocks (remapped so all 16 q-tiles of one bh share an XCD), 256 threads = 4 waves.
// Wave w: q rows [qt*128 + w*32, +32). Per kv-tile (64): K,V^T staged in swizzled LDS
// (double-buffered, global_load_lds w/ inverse-swizzled source), shared by all 4 waves.
// S^T = K*Q^T (lane owns q = lane&31); softmax lane-local; P^T built in-register
// (cvt_pk + permlane32_swap); O^T = V^T * P^T.
__global__ __launch_bounds__(256, 2) void flash3_kernel(
    const u16* __restrict__ qg, const u16* __restrict__ kg, const u16* __restrict__ vtg,
    u16* __restrict__ o) {
    __shared__ __align__(16) u16 Kl[2][64 * 64];
    __shared__ __align__(16) u16 Vl[2][64 * 64];

    int tid = threadIdx.x, lane = tid & 63, w = tid >> 6;
    int l31 = lane & 31, hi = lane >> 5;
    int p = blockIdx.y * 16 + blockIdx.x;
    int bh = p & 31, qt = p >> 5;        // XCD-local: all q-tiles of bh on one XCD
    int q0 = qt * 128 + w * 32;

    const u16* qp = qg + ((size_t)bh * 2048 + q0 + l31) * 64 + hi * 8;
    bf16x8 qf[4];
#pragma unroll
    for (int ds = 0; ds < 4; ds++)
        qf[ds] = *reinterpret_cast<const bf16x8*>(qp + ds * 16);

    const char* kb = (const char*)(kg + (size_t)bh * 2048 * 64);
    const char* vb = (const char*)(vtg + (size_t)bh * 64 * 2048);

    f32x16 accO[2];
#pragma unroll
    for (int db = 0; db < 2; db++)
#pragma unroll
        for (int r = 0; r < 16; r++) accO[db][r] = 0.f;
    float m = -1e30f, lsum = 0.f;

    // stage tile t into buffer b: wave w covers bytes [w*2048, w*2048+2048) of each 8KB tile
#define STAGE(bb, tt)                                                                   \
    {                                                                                   \
        const char* ktile = kb + (size_t)(tt) * 8192;                                   \
        _Pragma("unroll") for (int i = 0; i < 2; i++) {                                 \
            int od = w * 2048 + i * 1024 + lane * 16;                                   \
            int ks_ = od ^ (((od >> 7) & 7) << 4);                                      \
            gload_lds16(ktile + ks_, (char*)Kl[bb] + w * 2048 + i * 1024);              \
            int vr = od >> 7;                                                           \
            int vc = (od & 127) ^ ((vr & 7) << 4);                                      \
            gload_lds16(vb + (size_t)vr * 4096 + (size_t)(tt) * 128 + vc,               \
                        (char*)Vl[bb] + w * 2048 + i * 1024);                           \
        }                                                                               \
    }

    STAGE(0, 0);
    __syncthreads();

    int buf = 0;
    for (int t = 0; t < 32; t++) {
        if (t < 31) STAGE(buf ^ 1, t + 1);

        const u16* Kb_ = Kl[buf];
        const u16* Vb_ = Vl[buf];
        bf16x8 ka[2][4], va[2][4];
#pragma unroll
        for (int kvb = 0; kvb < 2; kvb++)
#pragma unroll
            for (int ds = 0; ds < 4; ds++)
                ka[kvb][ds] = swz_load16(Kb_, kvb * 32 + l31, ds * 32 + hi * 16);
#pragma unroll
        for (int db = 0; db < 2; db++)
#pragma unroll
            for (int ks = 0; ks < 4; ks++)
                va[db][ks] = swz_load16(Vb_, db * 32 + l31, ks * 32 + hi * 16);

        f32x16 s[2];
#pragma unroll
        for (int kvb = 0; kvb < 2; kvb++) {
#pragma unroll
            for (int r = 0; r < 16; r++) s[kvb][r] = 0.f;
#pragma unroll
            for (int ds = 0; ds < 4; ds++)
                s[kvb] = __builtin_amdgcn_mfma_f32_32x32x16_bf16(ka[kvb][ds], qf[ds], s[kvb], 0, 0, 0);
        }

        // lane-local online softmax (log2 domain; Q pre-scaled by 0.125*log2e)
        float mx = s[0][0];
#pragma unroll
        for (int kvb = 0; kvb < 2; kvb++)
#pragma unroll
            for (int r = 0; r < 16; r++) mx = fmaxf(mx, s[kvb][r]);
        mx = fmaxf(mx, __shfl_xor(mx, 32));
        float mnew = fmaxf(m, mx);
        float al = exp2f_fast(m - mnew);
        m = mnew;
        float rs = 0.f;
#pragma unroll
        for (int kvb = 0; kvb < 2; kvb++)
#pragma unroll
            for (int r = 0; r < 16; r++) {
                s[kvb][r] = exp2f_fast(s[kvb][r] - mnew);
                rs += s[kvb][r];
            }
        rs += __shfl_xor(rs, 32);
        lsum = lsum * al + rs;
#pragma unroll
        for (int db = 0; db < 2; db++)
#pragma unroll
            for (int r = 0; r < 16; r++) accO[db][r] *= al;

        // P^T B-frags in-register: pb[ks][j] = P[q][16ks+8hi+j]
        bf16x8 pb[4];
#pragma unroll
        for (int kvb = 0; kvb < 2; kvb++) {
            u32 x0 = cvtpk(s[kvb][0], s[kvb][1]),   y0 = cvtpk(s[kvb][4], s[kvb][5]);
            u32 x1 = cvtpk(s[kvb][2], s[kvb][3]),   y1 = cvtpk(s[kvb][6], s[kvb][7]);
            u32 x2 = cvtpk(s[kvb][8], s[kvb][9]),   y2 = cvtpk(s[kvb][12], s[kvb][13]);
            u32 x3 = cvtpk(s[kvb][10], s[kvb][11]), y3 = cvtpk(s[kvb][14], s[kvb][15]);
            plswap(x0, y0); plswap(x1, y1); plswap(x2, y2); plswap(x3, y3);
            u32x4v plo = {x0, x1, y0, y1};
            u32x4v phi = {x2, x3, y2, y3};
            pb[2 * kvb] = __builtin_bit_cast(bf16x8, plo);
            pb[2 * kvb + 1] = __builtin_bit_cast(bf16x8, phi);
        }

#pragma unroll
        for (int db = 0; db < 2; db++)
#pragma unroll
            for (int ks = 0; ks < 4; ks++)
                accO[db] = __builtin_amdgcn_mfma_f32_32x32x16_bf16(va[db][ks], pb[ks], accO[db], 0, 0, 0);

        __syncthreads();
        buf ^= 1;
    }
#undef STAGE

    // O^T[d][q]: lane owns q = lane&31, d = (r&3)+8(r>>2)+4hi+32db. Store d-pairs as u32.
    float inv = 1.f / lsum;
    int b = bh >> 4, h = bh & 15;
    u16* ob = o + ((size_t)(b * 2048 + q0 + l31)) * 1024 + h * 64;
#pragma unroll
    for (int db = 0; db < 2; db++)
#pragma unroll
        for (int i = 0; i < 8; i++) {
            int r = 2 * i;
            int d = (r & 3) + 8 * (r >> 2) + 4 * hi + 32 * db;
            u32 pk = cvtpk(accO[db][r] * inv, accO[db][r + 1] * inv);
            *reinterpret_cast<u32*>(ob + d) = pk;
        }
}

// ---------------- launch ----------------

extern "C" void kernel_launch(void* const* d_in, const int* in_sizes, int n_in,
                              void* d_out, int out_size, void* d_ws, size_t ws_size,
                              hipStream_t stream) {
    (void)in_sizes; (void)n_in; (void)out_size; (void)ws_size;
    const float* x = (const float*)d_in[0];
    const float* w_qkv = (const float*)d_in[1];
    const float* w_proj = (const float*)d_in[2];
    const float* b_proj = (const float*)d_in[3];
    float* out = (float*)d_out;
    char* ws = (char*)d_ws;

    u16* xb   = (u16*)(ws + 0);            // 4096x1024 bf16
    u16* wqt  = (u16*)(ws + 8388608);      // 3072x1024 bf16
    u16* wpt  = (u16*)(ws + 14680064);     // 1024x1024 bf16
    u16* qws  = (u16*)(ws + 16777216);     // [32][2048][64] bf16 (pre-scaled by 0.125*log2e)
    u16* kws  = (u16*)(ws + 25165824);
    u16* vws  = (u16*)(ws + 33554432);
    u16* vtws = (u16*)(ws + 41943040);     // [32][64][2048] bf16
    u16* attn = (u16*)(ws + 50331648);     // [4096][1024] bf16

    cvt_x_kernel<<<2048, 256, 0, stream>>>(x, xb);
    trw_kernel<<<dim3(96, 32), dim3(32, 8), 0, stream>>>(w_qkv, wqt, 1024, 3072);
    trw_kernel<<<dim3(32, 32), dim3(32, 8), 0, stream>>>(w_proj, wpt, 1024, 1024);
    gemm_kernel<0><<<32 * 24, 256, 0, stream>>>(xb, wqt, 24, qws, kws, vws, nullptr, nullptr);
    trv_kernel<<<dim3(32, 32), 256, 0, stream>>>(vws, vtws);
    flash3_kernel<<<dim3(16, 32), 256, 0, stream>>>(qws, kws, vtws, attn);
    gemm_kernel<1><<<32 * 8, 256, 0, stream>>>(attn, wpt, 8, nullptr, nullptr, nullptr, out, b_proj);
}